// Round 15
// baseline (488.582 us; speedup 1.0000x reference)
//
#include <hip/hip_runtime.h>
#include <hip/hip_bf16.h>
#include <math.h>

#define N_NODES 100000
#define N_EDGES 1600000
#define D_IN 512
#define D_HID 256
#define D_OUT 40
#define S2_LD 48   // support2 leading dim in bf16 elements (96B rows)
#define SCAN_BLOCKS ((N_NODES + 255) / 256)   // 391
#define NSHADOW 8

// L1 merged-prep block ranges (512 threads each)
#define XCONV_BLOCKS 12500                         // 51.2M elems / (512*8)
#define HIST_BLOCKS ((N_EDGES + 511) / 512)        // 3125
#define W1T_BLOCKS 256                             // 131072 / 512
#define W2T_BLOCKS 24                              // 12288 / 512

// L3 merged ranges (256 threads each)
#define G1_BLOCKS ((N_NODES + 63) / 64)            // 1563
#define SCAT_BLOCKS ((N_EDGES + 255) / 256)        // 6250

typedef short short8 __attribute__((ext_vector_type(8)));
typedef short short16 __attribute__((ext_vector_type(16)));
typedef short short4v __attribute__((ext_vector_type(4)));
typedef float f32x4 __attribute__((ext_vector_type(4)));

// f32 -> bf16 via native cast (RNE)
static __device__ __forceinline__ short f2bf(float f) {
  union { __hip_bfloat16 b; short s; } u;
  u.b = __float2bfloat16(f);
  return u.s;
}
static __device__ __forceinline__ float bf2f(unsigned short h) {
  return __uint_as_float(((unsigned)h) << 16);
}

// ---------------------------------------------------------------------------
// Threefry-2x32, 20 rounds, key = (0, 42)
// ---------------------------------------------------------------------------
static __device__ __forceinline__ void threefry_0_42(unsigned x0, unsigned x1,
                                                     unsigned& o0, unsigned& o1) {
  const unsigned ks0 = 0u;
  const unsigned ks1 = 42u;
  const unsigned ks2 = 0u ^ 42u ^ 0x1BD11BDAu;
  x0 += ks0; x1 += ks1;
#define TF_R(r) { x0 += x1; x1 = (x1 << (r)) | (x1 >> (32 - (r))); x1 ^= x0; }
  TF_R(13) TF_R(15) TF_R(26) TF_R(6)
  x0 += ks1; x1 += ks2 + 1u;
  TF_R(17) TF_R(29) TF_R(16) TF_R(24)
  x0 += ks2; x1 += ks0 + 2u;
  TF_R(13) TF_R(15) TF_R(26) TF_R(6)
  x0 += ks0; x1 += ks1 + 3u;
  TF_R(17) TF_R(29) TF_R(16) TF_R(24)
  x0 += ks1; x1 += ks2 + 4u;
  TF_R(13) TF_R(15) TF_R(26) TF_R(6)
  x0 += ks2; x1 += ks0 + 5u;
#undef TF_R
  o0 = x0; o1 = x1;
}

// ---------------------------------------------------------------------------
// L1 mega-prep: x->bf16 (blocks 0..12499) + shadow hist (next 3125) +
//               W1t transpose (next 256) + W2t pad (next 24)
// All depend only on kernel inputs — fully parallel in one launch.
// ---------------------------------------------------------------------------
__global__ __launch_bounds__(512) void prep_kernel(
    const float* __restrict__ x, short* __restrict__ xb,
    const int* __restrict__ edst, int* __restrict__ counts8,
    const float* __restrict__ W1, short* __restrict__ W1t,
    const float* __restrict__ W2, short* __restrict__ W2t) {
  const int bid = blockIdx.x;
  const int tid = threadIdx.x;

  if (bid < XCONV_BLOCKS) {
    const size_t i0 = ((size_t)bid * 512 + tid) * 8;
    const float4 f0 = *(const float4*)(x + i0);
    const float4 f1 = *(const float4*)(x + i0 + 4);
    short8 v;
    v[0] = f2bf(f0.x); v[1] = f2bf(f0.y); v[2] = f2bf(f0.z); v[3] = f2bf(f0.w);
    v[4] = f2bf(f1.x); v[5] = f2bf(f1.y); v[6] = f2bf(f1.z); v[7] = f2bf(f1.w);
    *(short8*)(xb + i0) = v;
    return;
  }
  int xb2 = bid - XCONV_BLOCKS;
  if (xb2 < HIST_BLOCKS) {
    const int e = xb2 * 512 + tid;
    if (e < N_EDGES) atomicAdd(&counts8[(xb2 & 7) * N_NODES + edst[e]], 1);
    return;
  }
  xb2 -= HIST_BLOCKS;
  if (xb2 < W1T_BLOCKS) {
    const int i = xb2 * 512 + tid;
    const int n = i >> 9;
    const int k = i & 511;
    W1t[i] = f2bf(W1[(size_t)k * D_HID + n]);
    return;
  }
  xb2 -= W1T_BLOCKS;
  {
    const int j = xb2 * 512 + tid;
    if (j < 48 * D_HID) {
      const int n = j >> 8;
      const int k = j & 255;
      W2t[j] = (n < D_OUT) ? f2bf(W2[(size_t)k * D_OUT + n]) : (short)0;
    }
  }
}

// ---------------------------------------------------------------------------
// CSR scan stages (counts8 -> counts_tot -> rowptr/cursor)
// ---------------------------------------------------------------------------
__global__ __launch_bounds__(256) void block_sum_kernel(const int* __restrict__ counts8,
                                                        int* __restrict__ counts_tot,
                                                        int* __restrict__ bsums) {
  __shared__ int red[256];
  const int t = threadIdx.x;
  const int i = blockIdx.x * 256 + t;
  int c = 0;
  if (i < N_NODES) {
#pragma unroll
    for (int s = 0; s < NSHADOW; ++s) c += counts8[s * N_NODES + i];
    counts_tot[i] = c;
  }
  red[t] = c;
  __syncthreads();
#pragma unroll
  for (int off = 128; off > 0; off >>= 1) {
    if (t < off) red[t] += red[t + off];
    __syncthreads();
  }
  if (t == 0) bsums[blockIdx.x] = red[0];
}

__global__ __launch_bounds__(512) void bsum_scan_kernel(const int* __restrict__ bsums,
                                                        int* __restrict__ boffs) {
  __shared__ int tmp[512];
  const int t = threadIdx.x;
  const int v = (t < SCAN_BLOCKS) ? bsums[t] : 0;
  tmp[t] = v;
  __syncthreads();
  for (int off = 1; off < 512; off <<= 1) {
    const int add = (t >= off) ? tmp[t - off] : 0;
    __syncthreads();
    tmp[t] += add;
    __syncthreads();
  }
  if (t < SCAN_BLOCKS) boffs[t] = tmp[t] - v;
}

__global__ __launch_bounds__(256) void scan_apply_kernel(const int* __restrict__ counts_tot,
                                                         const int* __restrict__ boffs,
                                                         int* __restrict__ rowptr,
                                                         int* __restrict__ cursor) {
  __shared__ int tmp[256];
  const int t = threadIdx.x;
  const int i = blockIdx.x * 256 + t;
  const int v = (i < N_NODES) ? counts_tot[i] : 0;
  tmp[t] = v;
  __syncthreads();
  for (int off = 1; off < 256; off <<= 1) {
    const int add = (t >= off) ? tmp[t - off] : 0;
    __syncthreads();
    tmp[t] += add;
    __syncthreads();
  }
  const int excl = boffs[blockIdx.x] + tmp[t] - v;
  if (i < N_NODES) {
    rowptr[i] = excl;
    cursor[i] = excl;
    if (i == N_NODES - 1) rowptr[N_NODES] = excl + v;
  }
}

// ---------------------------------------------------------------------------
// L3 merged: gemm1 (blocks 0..1562, BM=64 BN=256 BK=32, 4 waves) +
//            scatter (next 6250 blocks)
// gemm1: support1(bf16)[100000,256] = xb(bf16) @ W1
// ---------------------------------------------------------------------------
__global__ __launch_bounds__(256) void gemm1_scatter_kernel(
    const short* __restrict__ xb, const short* __restrict__ W1t,
    short* __restrict__ out,
    const int* __restrict__ esrc, const int* __restrict__ edst,
    const float* __restrict__ ew, int* __restrict__ cursor,
    int2* __restrict__ pairs) {
  const int bid = blockIdx.x;
  const int tid = threadIdx.x;

  if (bid >= G1_BLOCKS) {
    // scatter: dst-sorted (src, weight) pairs, one 8B store
    const int e = (bid - G1_BLOCKS) * 256 + tid;
    if (e < N_EDGES) {
      const int d = edst[e];
      const int pos = atomicAdd(&cursor[d], 1);
      int2 p;
      p.x = esrc[e];
      p.y = __float_as_int(ew[e]);
      pairs[pos] = p;
    }
    return;
  }

  __shared__ __attribute__((aligned(16))) short As[64][40];
  __shared__ __attribute__((aligned(16))) short Bs[256][40];

  const int lane = tid & 63;
  const int wn   = tid >> 6;       // 0..3 — N-quadrant of 64 cols
  const int lr   = lane & 15;
  const int lg   = lane >> 4;
  const int row0 = bid * 64;

  f32x4 acc[4][4] = {};

  for (int kt = 0; kt < D_IN; kt += 32) {
    // stage A: 64 rows x 32 k bf16; thread: row m=tid>>2, chunk kc=tid&3
    {
      const int m  = tid >> 2;
      const int kc = tid & 3;
      const int grow = row0 + m;
      short8 v = (short8)0;
      if (grow < N_NODES)
        v = *(const short8*)(xb + (size_t)grow * D_IN + kt + kc * 8);
      *(short8*)&As[m][kc * 8] = v;
    }
    // stage B: 256 rows x 32 k; thread tid handles row tid (64B)
    {
      const short* bs = W1t + (size_t)tid * D_IN + kt;
      const short16 b0 = *(const short16*)(bs);
      const short16 b1 = *(const short16*)(bs + 16);
      *(short16*)&Bs[tid][0]  = b0;
      *(short16*)&Bs[tid][16] = b1;
    }
    __syncthreads();

    short8 a[4], b[4];
#pragma unroll
    for (int mi = 0; mi < 4; ++mi)
      a[mi] = *(const short8*)&As[mi * 16 + lr][lg * 8];
#pragma unroll
    for (int nj = 0; nj < 4; ++nj)
      b[nj] = *(const short8*)&Bs[wn * 64 + nj * 16 + lr][lg * 8];

#pragma unroll
    for (int mi = 0; mi < 4; ++mi)
#pragma unroll
      for (int nj = 0; nj < 4; ++nj)
        acc[mi][nj] = __builtin_amdgcn_mfma_f32_16x16x32_bf16(a[mi], b[nj], acc[mi][nj], 0, 0, 0);

    __syncthreads();
  }

#pragma unroll
  for (int mi = 0; mi < 4; ++mi) {
#pragma unroll
    for (int nj = 0; nj < 4; ++nj) {
      const int gcol = wn * 64 + nj * 16 + lr;
#pragma unroll
      for (int r = 0; r < 4; ++r) {
        const int grow = row0 + mi * 16 + lg * 4 + r;
        if (grow < N_NODES) out[(size_t)grow * D_HID + gcol] = f2bf(acc[mi][nj][r]);
      }
    }
  }
}

// ---------------------------------------------------------------------------
// SpMM1 (CSR) + fused bias + ReLU + dropout; bf16 in/out, f32 accum.
// Wave = two 32-lane halves; half h walks edges beg+h, beg+h+2, ...
// ---------------------------------------------------------------------------
__global__ __launch_bounds__(256) void spmm1_csr_kernel(const short* __restrict__ sup,
                                                        const int* __restrict__ rowptr,
                                                        const int2* __restrict__ pairs,
                                                        const float* __restrict__ b1,
                                                        short* __restrict__ h) {
  const int node = blockIdx.x * 4 + (threadIdx.x >> 6);
  const int lane = threadIdx.x & 63;
  const int half = lane >> 5;
  const int hl   = lane & 31;
  if (node >= N_NODES) return;
  const int beg = rowptr[node];
  const int end = rowptr[node + 1];

  float acc[8] = {};

  int e = beg + half;
  for (; e + 6 < end; e += 8) {
    const int2 p0 = pairs[e];
    const int2 p1 = pairs[e + 2];
    const int2 p2 = pairs[e + 4];
    const int2 p3 = pairs[e + 6];
    const short8 v0 = *(const short8*)(sup + (size_t)p0.x * D_HID + hl * 8);
    const short8 v1 = *(const short8*)(sup + (size_t)p1.x * D_HID + hl * 8);
    const short8 v2 = *(const short8*)(sup + (size_t)p2.x * D_HID + hl * 8);
    const short8 v3 = *(const short8*)(sup + (size_t)p3.x * D_HID + hl * 8);
    const float w0 = __int_as_float(p0.y);
    const float w1 = __int_as_float(p1.y);
    const float w2 = __int_as_float(p2.y);
    const float w3 = __int_as_float(p3.y);
#pragma unroll
    for (int j = 0; j < 8; ++j) acc[j] += w0 * bf2f((unsigned short)v0[j]);
#pragma unroll
    for (int j = 0; j < 8; ++j) acc[j] += w1 * bf2f((unsigned short)v1[j]);
#pragma unroll
    for (int j = 0; j < 8; ++j) acc[j] += w2 * bf2f((unsigned short)v2[j]);
#pragma unroll
    for (int j = 0; j < 8; ++j) acc[j] += w3 * bf2f((unsigned short)v3[j]);
  }
  for (; e < end; e += 2) {
    const int2 p0 = pairs[e];
    const float w0 = __int_as_float(p0.y);
    const short8 v0 = *(const short8*)(sup + (size_t)p0.x * D_HID + hl * 8);
#pragma unroll
    for (int j = 0; j < 8; ++j) acc[j] += w0 * bf2f((unsigned short)v0[j]);
  }

#pragma unroll
  for (int j = 0; j < 8; ++j) acc[j] += __shfl_xor(acc[j], 32, 64);

  const int col = hl * 8 + half * 4;
  short4v r;
#pragma unroll
  for (int j = 0; j < 4; ++j) {
    float v = acc[half * 4 + j] + b1[col + j];
    v = v > 0.0f ? v : 0.0f;
    unsigned o0, o1;
    threefry_0_42(0u, (unsigned)node * D_HID + col + j, o0, o1);
    const unsigned word = o0 ^ o1;
    r[j] = (word >> 31) ? (short)0 : f2bf(v * 2.0f);
  }
  *(short4v*)(h + (size_t)node * D_HID + col) = r;
}

// ---------------------------------------------------------------------------
// GEMM2 (bf16 MFMA): support2(bf16, stride S2_LD)[100000] = h(bf16) @ W2
// ---------------------------------------------------------------------------
__global__ __launch_bounds__(256) void gemm2_mfma_kernel(const short* __restrict__ h,
                                                         const short* __restrict__ W2t,
                                                         short* __restrict__ out) {
  __shared__ __attribute__((aligned(16))) short As[128][40];
  __shared__ __attribute__((aligned(16))) short Bs[48][40];

  const int tid  = threadIdx.x;
  const int lane = tid & 63;
  const int wm   = tid >> 6;
  const int lr   = lane & 15;
  const int lg   = lane >> 4;
  const int row0 = blockIdx.x * 128;

  f32x4 acc[2][3] = {};

  for (int kt = 0; kt < D_HID; kt += 32) {
    {
#pragma unroll
      for (int c = 0; c < 2; ++c) {
        const int t2 = (tid << 1) | c;
        const int m  = t2 >> 2;
        const int kc = t2 & 3;
        const int grow = row0 + m;
        short8 v = (short8)0;
        if (grow < N_NODES)
          v = *(const short8*)(h + (size_t)grow * D_HID + kt + kc * 8);
        *(short8*)&As[m][kc * 8] = v;
      }
    }
    if (tid < 192) {
      const int n  = tid >> 2;
      const int kc = tid & 3;
      const short8 v = *(const short8*)(W2t + (size_t)n * D_HID + kt + kc * 8);
      *(short8*)&Bs[n][kc * 8] = v;
    }
    __syncthreads();

    short8 a[2], b[3];
#pragma unroll
    for (int mi = 0; mi < 2; ++mi)
      a[mi] = *(const short8*)&As[wm * 32 + mi * 16 + lr][lg * 8];
#pragma unroll
    for (int nj = 0; nj < 3; ++nj)
      b[nj] = *(const short8*)&Bs[nj * 16 + lr][lg * 8];

#pragma unroll
    for (int mi = 0; mi < 2; ++mi)
#pragma unroll
      for (int nj = 0; nj < 3; ++nj)
        acc[mi][nj] = __builtin_amdgcn_mfma_f32_16x16x32_bf16(a[mi], b[nj], acc[mi][nj], 0, 0, 0);

    __syncthreads();
  }

#pragma unroll
  for (int mi = 0; mi < 2; ++mi) {
#pragma unroll
    for (int nj = 0; nj < 3; ++nj) {
      const int gcol = nj * 16 + lr;
      if (gcol < D_OUT) {
#pragma unroll
        for (int r = 0; r < 4; ++r) {
          const int grow = row0 + wm * 32 + mi * 16 + lg * 4 + r;
          if (grow < N_NODES) out[(size_t)grow * S2_LD + gcol] = f2bf(acc[mi][nj][r]);
        }
      }
    }
  }
}

// ---------------------------------------------------------------------------
// SpMM2 (CSR, bf16, stride S2_LD) + fused bias + log_softmax -> d_out
// Two nodes per wave (one per 32-lane half), 2 feats/lane (uint = 2 bf16).
// ---------------------------------------------------------------------------
__global__ __launch_bounds__(256) void spmm2_csr_kernel(const short* __restrict__ sup2,
                                                        const int* __restrict__ rowptr,
                                                        const int2* __restrict__ pairs,
                                                        const float* __restrict__ b2,
                                                        float* __restrict__ out) {
  const int lane = threadIdx.x & 63;
  const int half = lane >> 5;
  const int hl   = lane & 31;
  const int node = blockIdx.x * 8 + ((threadIdx.x >> 6) << 1) + half;
  if (node >= N_NODES) return;
  const int beg = rowptr[node];
  const int end = rowptr[node + 1];
  const bool act = hl < 20;

  float a0 = 0.f, a1 = 0.f, b0 = 0.f, b1 = 0.f;
  float c0 = 0.f, c1 = 0.f, d0 = 0.f, d1 = 0.f;
  int e = beg;
  for (; e + 4 <= end; e += 4) {
    const int2 p0 = pairs[e], p1 = pairs[e + 1], p2 = pairs[e + 2], p3 = pairs[e + 3];
    if (act) {
      const unsigned u0 = *(const unsigned*)(sup2 + (size_t)p0.x * S2_LD + hl * 2);
      const unsigned u1 = *(const unsigned*)(sup2 + (size_t)p1.x * S2_LD + hl * 2);
      const unsigned u2 = *(const unsigned*)(sup2 + (size_t)p2.x * S2_LD + hl * 2);
      const unsigned u3 = *(const unsigned*)(sup2 + (size_t)p3.x * S2_LD + hl * 2);
      const float w0 = __int_as_float(p0.y);
      const float w1 = __int_as_float(p1.y);
      const float w2 = __int_as_float(p2.y);
      const float w3 = __int_as_float(p3.y);
      a0 += w0 * bf2f((unsigned short)(u0 & 0xffff)); a1 += w0 * bf2f((unsigned short)(u0 >> 16));
      b0 += w1 * bf2f((unsigned short)(u1 & 0xffff)); b1 += w1 * bf2f((unsigned short)(u1 >> 16));
      c0 += w2 * bf2f((unsigned short)(u2 & 0xffff)); c1 += w2 * bf2f((unsigned short)(u2 >> 16));
      d0 += w3 * bf2f((unsigned short)(u3 & 0xffff)); d1 += w3 * bf2f((unsigned short)(u3 >> 16));
    }
  }
  for (; e < end; ++e) {
    const int2 p0 = pairs[e];
    if (act) {
      const unsigned u0 = *(const unsigned*)(sup2 + (size_t)p0.x * S2_LD + hl * 2);
      const float w0 = __int_as_float(p0.y);
      a0 += w0 * bf2f((unsigned short)(u0 & 0xffff)); a1 += w0 * bf2f((unsigned short)(u0 >> 16));
    }
  }
  const float f0 = (a0 + b0) + (c0 + d0);
  const float f1 = (a1 + b1) + (c1 + d1);

  const float v0 = act ? f0 + b2[hl * 2]     : -INFINITY;
  const float v1 = act ? f1 + b2[hl * 2 + 1] : -INFINITY;
  float m = fmaxf(v0, v1);
#pragma unroll
  for (int off = 16; off > 0; off >>= 1) m = fmaxf(m, __shfl_xor(m, off, 32));
  float s = act ? __expf(v0 - m) + __expf(v1 - m) : 0.0f;
#pragma unroll
  for (int off = 16; off > 0; off >>= 1) s += __shfl_xor(s, off, 32);
  if (act) {
    const float ls = logf(s);
    float2 r;
    r.x = v0 - m - ls;
    r.y = v1 - m - ls;
    *(float2*)&out[(size_t)node * D_OUT + hl * 2] = r;
  }
}

// ---------------------------------------------------------------------------
extern "C" void kernel_launch(void* const* d_in, const int* in_sizes, int n_in,
                              void* d_out, int out_size, void* d_ws, size_t ws_size,
                              hipStream_t stream) {
  const float* x    = (const float*)d_in[0];
  const int*   esrc = (const int*)d_in[1];
  const int*   edst = (const int*)d_in[2];
  const float* ew   = (const float*)d_in[3];
  const float* W1   = (const float*)d_in[4];
  const float* b1   = (const float*)d_in[5];
  const float* W2   = (const float*)d_in[6];
  const float* b2   = (const float*)d_in[7];
  float* out = (float*)d_out;

  float* ws = (float*)d_ws;
  short* support1 = (short*)ws;                  // 25.6M bf16 (51.2 MB)
  short* xb       = (short*)(ws + 12800000);     // 51.2M bf16 (102.4 MB) — dead after gemm1
  short* hbuf     = xb;                          // ALIASES xb (hbuf written only after xb dead)
  short* support2 = (short*)(ws + 38400000);     //  4.8M bf16 (9.6 MB, stride 48)
  int2*  pairs    = (int2*)(ws + 40800000);      //  1.6M int2 (12.8 MB)
  int*   rowptr   = (int*)(ws + 44000000);       //    100,001 i
  int*   counts_t = (int*)(ws + 44100008);       //    100,000 i
  int*   cursor   = (int*)(ws + 44200008);       //    100,000 i
  short* W1t      = (short*)(ws + 44300008);     //    131,072 bf16
  short* W2t      = (short*)(ws + 44365544);     //     12,288 bf16
  int*   bsums    = (int*)(ws + 44371688);       //        391 i
  int*   boffs    = bsums + 512;
  int*   counts8  = (int*)(ws + 44372712);       //    800,000 i (8 shadows)

  hipMemsetAsync(counts8, 0, (size_t)NSHADOW * N_NODES * sizeof(int), stream);

  // L1: x->bf16 + shadow hist + W1t + W2t (all input-only, one launch)
  prep_kernel<<<XCONV_BLOCKS + HIST_BLOCKS + W1T_BLOCKS + W2T_BLOCKS, 512, 0, stream>>>(
      x, xb, edst, counts8, W1, W1t, W2, W2t);

  // L2: CSR scan
  block_sum_kernel<<<SCAN_BLOCKS, 256, 0, stream>>>(counts8, counts_t, bsums);
  bsum_scan_kernel<<<1, 512, 0, stream>>>(bsums, boffs);
  scan_apply_kernel<<<SCAN_BLOCKS, 256, 0, stream>>>(counts_t, boffs, rowptr, cursor);

  // L3: gemm1 (bf16 in) + scatter merged
  gemm1_scatter_kernel<<<G1_BLOCKS + SCAT_BLOCKS, 256, 0, stream>>>(
      xb, W1t, support1, esrc, edst, ew, cursor, pairs);

  // L4: layer-1 aggregation (+bias/ReLU/dropout)
  spmm1_csr_kernel<<<(N_NODES + 3) / 4, 256, 0, stream>>>(support1, rowptr, pairs, b1, hbuf);

  // L5/L6: layer 2
  gemm2_mfma_kernel<<<(N_NODES + 127) / 128, 256, 0, stream>>>(hbuf, W2t, support2);
  spmm2_csr_kernel<<<(N_NODES + 7) / 8, 256, 0, stream>>>(support2, rowptr, pairs, b2, out);
}

// Round 16
// 426.110 us; speedup vs baseline: 1.1466x; 1.1466x over previous
//
#include <hip/hip_runtime.h>
#include <hip/hip_bf16.h>
#include <math.h>

#define N_NODES 100000
#define N_EDGES 1600000
#define D_IN 512
#define D_HID 256
#define D_OUT 40
#define S2_LD 48   // support2 leading dim in bf16 elements (96B rows)
#define SCAN_BLOCKS ((N_NODES + 255) / 256)   // 391
#define NSHADOW 8

#define G1_BLOCKS ((N_NODES + 127) / 128)          // 782
#define HIST_BLOCKS ((N_EDGES + 511) / 512)        // 3125
#define W2T_N (48 * D_HID)                         // 12288
#define W2T_BLOCKS ((W2T_N + 511) / 512)           // 24

typedef short short8 __attribute__((ext_vector_type(8)));
typedef short short4v __attribute__((ext_vector_type(4)));
typedef float f32x4 __attribute__((ext_vector_type(4)));

// f32 -> bf16 via native cast (RNE)
static __device__ __forceinline__ short f2bf(float f) {
  union { __hip_bfloat16 b; short s; } u;
  u.b = __float2bfloat16(f);
  return u.s;
}
static __device__ __forceinline__ float bf2f(unsigned short h) {
  return __uint_as_float(((unsigned)h) << 16);
}

// ---------------------------------------------------------------------------
// Threefry-2x32, 20 rounds, key = (0, 42)
// ---------------------------------------------------------------------------
static __device__ __forceinline__ void threefry_0_42(unsigned x0, unsigned x1,
                                                     unsigned& o0, unsigned& o1) {
  const unsigned ks0 = 0u;
  const unsigned ks1 = 42u;
  const unsigned ks2 = 0u ^ 42u ^ 0x1BD11BDAu;
  x0 += ks0; x1 += ks1;
#define TF_R(r) { x0 += x1; x1 = (x1 << (r)) | (x1 >> (32 - (r))); x1 ^= x0; }
  TF_R(13) TF_R(15) TF_R(26) TF_R(6)
  x0 += ks1; x1 += ks2 + 1u;
  TF_R(17) TF_R(29) TF_R(16) TF_R(24)
  x0 += ks2; x1 += ks0 + 2u;
  TF_R(13) TF_R(15) TF_R(26) TF_R(6)
  x0 += ks0; x1 += ks1 + 3u;
  TF_R(17) TF_R(29) TF_R(16) TF_R(24)
  x0 += ks1; x1 += ks2 + 4u;
  TF_R(13) TF_R(15) TF_R(26) TF_R(6)
  x0 += ks2; x1 += ks0 + 5u;
#undef TF_R
  o0 = x0; o1 = x1;
}

// ---------------------------------------------------------------------------
// W1t prep (dedicated; precedes K1): W1 [512][256] f32 -> W1t [256][512] bf16
// ---------------------------------------------------------------------------
__global__ __launch_bounds__(512) void w1t_only_kernel(const float* __restrict__ W1,
                                                       short* __restrict__ W1t) {
  const int i = blockIdx.x * 512 + threadIdx.x;
  if (i >= D_IN * D_HID) return;
  const int n = i >> 9;
  const int k = i & 511;
  W1t[i] = f2bf(W1[(size_t)k * D_HID + n]);
}

// ---------------------------------------------------------------------------
// CSR build (scan stages) — counts8: 8 shadow histograms
// ---------------------------------------------------------------------------
__global__ __launch_bounds__(256) void block_sum_kernel(const int* __restrict__ counts8,
                                                        int* __restrict__ counts_tot,
                                                        int* __restrict__ bsums) {
  __shared__ int red[256];
  const int t = threadIdx.x;
  const int i = blockIdx.x * 256 + t;
  int c = 0;
  if (i < N_NODES) {
#pragma unroll
    for (int s = 0; s < NSHADOW; ++s) c += counts8[s * N_NODES + i];
    counts_tot[i] = c;
  }
  red[t] = c;
  __syncthreads();
#pragma unroll
  for (int off = 128; off > 0; off >>= 1) {
    if (t < off) red[t] += red[t + off];
    __syncthreads();
  }
  if (t == 0) bsums[blockIdx.x] = red[0];
}

__global__ __launch_bounds__(512) void bsum_scan_kernel(const int* __restrict__ bsums,
                                                        int* __restrict__ boffs) {
  __shared__ int tmp[512];
  const int t = threadIdx.x;
  const int v = (t < SCAN_BLOCKS) ? bsums[t] : 0;
  tmp[t] = v;
  __syncthreads();
  for (int off = 1; off < 512; off <<= 1) {
    const int add = (t >= off) ? tmp[t - off] : 0;
    __syncthreads();
    tmp[t] += add;
    __syncthreads();
  }
  if (t < SCAN_BLOCKS) boffs[t] = tmp[t] - v;
}

__global__ __launch_bounds__(256) void scan_apply_kernel(const int* __restrict__ counts_tot,
                                                         const int* __restrict__ boffs,
                                                         int* __restrict__ rowptr,
                                                         int* __restrict__ cursor) {
  __shared__ int tmp[256];
  const int t = threadIdx.x;
  const int i = blockIdx.x * 256 + t;
  const int v = (i < N_NODES) ? counts_tot[i] : 0;
  tmp[t] = v;
  __syncthreads();
  for (int off = 1; off < 256; off <<= 1) {
    const int add = (t >= off) ? tmp[t - off] : 0;
    __syncthreads();
    tmp[t] += add;
    __syncthreads();
  }
  const int excl = boffs[blockIdx.x] + tmp[t] - v;
  if (i < N_NODES) {
    rowptr[i] = excl;
    cursor[i] = excl;
    if (i == N_NODES - 1) rowptr[N_NODES] = excl + v;
  }
}

// Scatter edges into dst-sorted (src, weight) pairs — one 8B store
__global__ __launch_bounds__(256) void scatter_kernel(const int* __restrict__ esrc,
                                                      const int* __restrict__ edst,
                                                      const float* __restrict__ ew,
                                                      int* __restrict__ cursor,
                                                      int2* __restrict__ pairs) {
  const int e = blockIdx.x * 256 + threadIdx.x;
  if (e >= N_EDGES) return;
  const int d = edst[e];
  const int pos = atomicAdd(&cursor[d], 1);
  int2 p;
  p.x = esrc[e];
  p.y = __float_as_int(ew[e]);
  pairs[pos] = p;
}

// ---------------------------------------------------------------------------
// MERGED K1: gemm1 (blocks 0..781) + shadow hist (next 3125) + W2t prep (24)
// gemm1: support1(bf16)[100000,256] = x @ W1 ; BM=128,BN=256,BK=32, 8 waves
// ---------------------------------------------------------------------------
__global__ __launch_bounds__(512) void k1_gemm1_hist_w2t_kernel(
    const float* __restrict__ x, const short* __restrict__ W1t,
    short* __restrict__ out,
    const int* __restrict__ edst, int* __restrict__ counts8,
    const float* __restrict__ W2, short* __restrict__ W2t) {
  const int bid = blockIdx.x;
  const int tid = threadIdx.x;

  if (bid >= G1_BLOCKS) {
    const int xb = bid - G1_BLOCKS;
    if (xb < HIST_BLOCKS) {
      const int e = xb * 512 + tid;
      if (e < N_EDGES) atomicAdd(&counts8[(xb & 7) * N_NODES + edst[e]], 1);
    } else {
      const int j = (xb - HIST_BLOCKS) * 512 + tid;
      if (j < W2T_N) {
        const int n = j >> 8;
        const int k = j & 255;
        W2t[j] = (n < D_OUT) ? f2bf(W2[(size_t)k * D_OUT + n]) : (short)0;
      }
    }
    return;
  }

  __shared__ __attribute__((aligned(16))) short As[128][40];
  __shared__ __attribute__((aligned(16))) short Bs[256][40];

  const int lane = tid & 63;
  const int wid  = tid >> 6;
  const int wm   = wid >> 2;
  const int wn   = wid & 3;
  const int lr   = lane & 15;
  const int lg   = lane >> 4;
  const int row0 = bid * 128;

  f32x4 acc[4][4] = {};

  for (int kt = 0; kt < D_IN; kt += 32) {
    {
      const int m  = tid >> 2;
      const int kc = tid & 3;
      short8 v;
      const int grow = row0 + m;
      if (grow < N_NODES) {
        const float* src = x + (size_t)grow * D_IN + kt + kc * 8;
        const float4 f0 = *(const float4*)(src);
        const float4 f1 = *(const float4*)(src + 4);
        v[0] = f2bf(f0.x); v[1] = f2bf(f0.y); v[2] = f2bf(f0.z); v[3] = f2bf(f0.w);
        v[4] = f2bf(f1.x); v[5] = f2bf(f1.y); v[6] = f2bf(f1.z); v[7] = f2bf(f1.w);
      } else {
        v = (short8)0;
      }
      *(short8*)&As[m][kc * 8] = v;
    }
    {
#pragma unroll
      for (int c = 0; c < 2; ++c) {
        const int t2 = (tid << 1) | c;
        const int n  = t2 >> 2;
        const int kc = t2 & 3;
        const short8 v = *(const short8*)(W1t + (size_t)n * D_IN + kt + kc * 8);
        *(short8*)&Bs[n][kc * 8] = v;
      }
    }
    __syncthreads();

    short8 a[4], b[4];
#pragma unroll
    for (int mi = 0; mi < 4; ++mi)
      a[mi] = *(const short8*)&As[wm * 64 + mi * 16 + lr][lg * 8];
#pragma unroll
    for (int nj = 0; nj < 4; ++nj)
      b[nj] = *(const short8*)&Bs[wn * 64 + nj * 16 + lr][lg * 8];

#pragma unroll
    for (int mi = 0; mi < 4; ++mi)
#pragma unroll
      for (int nj = 0; nj < 4; ++nj)
        acc[mi][nj] = __builtin_amdgcn_mfma_f32_16x16x32_bf16(a[mi], b[nj], acc[mi][nj], 0, 0, 0);

    __syncthreads();
  }

#pragma unroll
  for (int mi = 0; mi < 4; ++mi) {
#pragma unroll
    for (int nj = 0; nj < 4; ++nj) {
      const int gcol = wn * 64 + nj * 16 + lr;
#pragma unroll
      for (int r = 0; r < 4; ++r) {
        const int grow = row0 + wm * 64 + mi * 16 + lg * 4 + r;
        if (grow < N_NODES) out[(size_t)grow * D_HID + gcol] = f2bf(acc[mi][nj][r]);
      }
    }
  }
}

// ---------------------------------------------------------------------------
// SpMM1 (CSR) + fused bias + ReLU + dropout; bf16 in/out, f32 accum.
// ---------------------------------------------------------------------------
__global__ __launch_bounds__(256) void spmm1_csr_kernel(const short* __restrict__ sup,
                                                        const int* __restrict__ rowptr,
                                                        const int2* __restrict__ pairs,
                                                        const float* __restrict__ b1,
                                                        short* __restrict__ h) {
  const int node = blockIdx.x * 4 + (threadIdx.x >> 6);
  const int lane = threadIdx.x & 63;
  const int half = lane >> 5;
  const int hl   = lane & 31;
  if (node >= N_NODES) return;
  const int beg = rowptr[node];
  const int end = rowptr[node + 1];

  float acc[8] = {};

  int e = beg + half;
  for (; e + 6 < end; e += 8) {
    const int2 p0 = pairs[e];
    const int2 p1 = pairs[e + 2];
    const int2 p2 = pairs[e + 4];
    const int2 p3 = pairs[e + 6];
    const short8 v0 = *(const short8*)(sup + (size_t)p0.x * D_HID + hl * 8);
    const short8 v1 = *(const short8*)(sup + (size_t)p1.x * D_HID + hl * 8);
    const short8 v2 = *(const short8*)(sup + (size_t)p2.x * D_HID + hl * 8);
    const short8 v3 = *(const short8*)(sup + (size_t)p3.x * D_HID + hl * 8);
    const float w0 = __int_as_float(p0.y);
    const float w1 = __int_as_float(p1.y);
    const float w2 = __int_as_float(p2.y);
    const float w3 = __int_as_float(p3.y);
#pragma unroll
    for (int j = 0; j < 8; ++j) acc[j] += w0 * bf2f((unsigned short)v0[j]);
#pragma unroll
    for (int j = 0; j < 8; ++j) acc[j] += w1 * bf2f((unsigned short)v1[j]);
#pragma unroll
    for (int j = 0; j < 8; ++j) acc[j] += w2 * bf2f((unsigned short)v2[j]);
#pragma unroll
    for (int j = 0; j < 8; ++j) acc[j] += w3 * bf2f((unsigned short)v3[j]);
  }
  for (; e < end; e += 2) {
    const int2 p0 = pairs[e];
    const float w0 = __int_as_float(p0.y);
    const short8 v0 = *(const short8*)(sup + (size_t)p0.x * D_HID + hl * 8);
#pragma unroll
    for (int j = 0; j < 8; ++j) acc[j] += w0 * bf2f((unsigned short)v0[j]);
  }

#pragma unroll
  for (int j = 0; j < 8; ++j) acc[j] += __shfl_xor(acc[j], 32, 64);

  const int col = hl * 8 + half * 4;
  short4v r;
#pragma unroll
  for (int j = 0; j < 4; ++j) {
    float v = acc[half * 4 + j] + b1[col + j];
    v = v > 0.0f ? v : 0.0f;
    unsigned o0, o1;
    threefry_0_42(0u, (unsigned)node * D_HID + col + j, o0, o1);
    const unsigned word = o0 ^ o1;
    r[j] = (word >> 31) ? (short)0 : f2bf(v * 2.0f);
  }
  *(short4v*)(h + (size_t)node * D_HID + col) = r;
}

// ---------------------------------------------------------------------------
// GEMM2 (bf16 MFMA): support2(bf16, stride S2_LD)[100000] = h(bf16) @ W2
// ---------------------------------------------------------------------------
__global__ __launch_bounds__(256) void gemm2_mfma_kernel(const short* __restrict__ h,
                                                         const short* __restrict__ W2t,
                                                         short* __restrict__ out) {
  __shared__ __attribute__((aligned(16))) short As[128][40];
  __shared__ __attribute__((aligned(16))) short Bs[48][40];

  const int tid  = threadIdx.x;
  const int lane = tid & 63;
  const int wm   = tid >> 6;
  const int lr   = lane & 15;
  const int lg   = lane >> 4;
  const int row0 = blockIdx.x * 128;

  f32x4 acc[2][3] = {};

  for (int kt = 0; kt < D_HID; kt += 32) {
    {
#pragma unroll
      for (int c = 0; c < 2; ++c) {
        const int t2 = (tid << 1) | c;
        const int m  = t2 >> 2;
        const int kc = t2 & 3;
        const int grow = row0 + m;
        short8 v = (short8)0;
        if (grow < N_NODES)
          v = *(const short8*)(h + (size_t)grow * D_HID + kt + kc * 8);
        *(short8*)&As[m][kc * 8] = v;
      }
    }
    if (tid < 192) {
      const int n  = tid >> 2;
      const int kc = tid & 3;
      const short8 v = *(const short8*)(W2t + (size_t)n * D_HID + kt + kc * 8);
      *(short8*)&Bs[n][kc * 8] = v;
    }
    __syncthreads();

    short8 a[2], b[3];
#pragma unroll
    for (int mi = 0; mi < 2; ++mi)
      a[mi] = *(const short8*)&As[wm * 32 + mi * 16 + lr][lg * 8];
#pragma unroll
    for (int nj = 0; nj < 3; ++nj)
      b[nj] = *(const short8*)&Bs[nj * 16 + lr][lg * 8];

#pragma unroll
    for (int mi = 0; mi < 2; ++mi)
#pragma unroll
      for (int nj = 0; nj < 3; ++nj)
        acc[mi][nj] = __builtin_amdgcn_mfma_f32_16x16x32_bf16(a[mi], b[nj], acc[mi][nj], 0, 0, 0);

    __syncthreads();
  }

#pragma unroll
  for (int mi = 0; mi < 2; ++mi) {
#pragma unroll
    for (int nj = 0; nj < 3; ++nj) {
      const int gcol = nj * 16 + lr;
      if (gcol < D_OUT) {
#pragma unroll
        for (int r = 0; r < 4; ++r) {
          const int grow = row0 + wm * 32 + mi * 16 + lg * 4 + r;
          if (grow < N_NODES) out[(size_t)grow * S2_LD + gcol] = f2bf(acc[mi][nj][r]);
        }
      }
    }
  }
}

// ---------------------------------------------------------------------------
// SpMM2 (CSR, bf16, stride S2_LD) + fused bias + log_softmax -> d_out
// ---------------------------------------------------------------------------
__global__ __launch_bounds__(256) void spmm2_csr_kernel(const short* __restrict__ sup2,
                                                        const int* __restrict__ rowptr,
                                                        const int2* __restrict__ pairs,
                                                        const float* __restrict__ b2,
                                                        float* __restrict__ out) {
  const int lane = threadIdx.x & 63;
  const int half = lane >> 5;
  const int hl   = lane & 31;
  const int node = blockIdx.x * 8 + ((threadIdx.x >> 6) << 1) + half;
  if (node >= N_NODES) return;
  const int beg = rowptr[node];
  const int end = rowptr[node + 1];
  const bool act = hl < 20;

  float a0 = 0.f, a1 = 0.f, b0 = 0.f, b1 = 0.f;
  float c0 = 0.f, c1 = 0.f, d0 = 0.f, d1 = 0.f;
  int e = beg;
  for (; e + 4 <= end; e += 4) {
    const int2 p0 = pairs[e], p1 = pairs[e + 1], p2 = pairs[e + 2], p3 = pairs[e + 3];
    if (act) {
      const unsigned u0 = *(const unsigned*)(sup2 + (size_t)p0.x * S2_LD + hl * 2);
      const unsigned u1 = *(const unsigned*)(sup2 + (size_t)p1.x * S2_LD + hl * 2);
      const unsigned u2 = *(const unsigned*)(sup2 + (size_t)p2.x * S2_LD + hl * 2);
      const unsigned u3 = *(const unsigned*)(sup2 + (size_t)p3.x * S2_LD + hl * 2);
      const float w0 = __int_as_float(p0.y);
      const float w1 = __int_as_float(p1.y);
      const float w2 = __int_as_float(p2.y);
      const float w3 = __int_as_float(p3.y);
      a0 += w0 * bf2f((unsigned short)(u0 & 0xffff)); a1 += w0 * bf2f((unsigned short)(u0 >> 16));
      b0 += w1 * bf2f((unsigned short)(u1 & 0xffff)); b1 += w1 * bf2f((unsigned short)(u1 >> 16));
      c0 += w2 * bf2f((unsigned short)(u2 & 0xffff)); c1 += w2 * bf2f((unsigned short)(u2 >> 16));
      d0 += w3 * bf2f((unsigned short)(u3 & 0xffff)); d1 += w3 * bf2f((unsigned short)(u3 >> 16));
    }
  }
  for (; e < end; ++e) {
    const int2 p0 = pairs[e];
    if (act) {
      const unsigned u0 = *(const unsigned*)(sup2 + (size_t)p0.x * S2_LD + hl * 2);
      const float w0 = __int_as_float(p0.y);
      a0 += w0 * bf2f((unsigned short)(u0 & 0xffff)); a1 += w0 * bf2f((unsigned short)(u0 >> 16));
    }
  }
  const float f0 = (a0 + b0) + (c0 + d0);
  const float f1 = (a1 + b1) + (c1 + d1);

  const float v0 = act ? f0 + b2[hl * 2]     : -INFINITY;
  const float v1 = act ? f1 + b2[hl * 2 + 1] : -INFINITY;
  float m = fmaxf(v0, v1);
#pragma unroll
  for (int off = 16; off > 0; off >>= 1) m = fmaxf(m, __shfl_xor(m, off, 32));
  float s = act ? __expf(v0 - m) + __expf(v1 - m) : 0.0f;
#pragma unroll
  for (int off = 16; off > 0; off >>= 1) s += __shfl_xor(s, off, 32);
  if (act) {
    const float ls = logf(s);
    float2 r;
    r.x = v0 - m - ls;
    r.y = v1 - m - ls;
    *(float2*)&out[(size_t)node * D_OUT + hl * 2] = r;
  }
}

// ---------------------------------------------------------------------------
extern "C" void kernel_launch(void* const* d_in, const int* in_sizes, int n_in,
                              void* d_out, int out_size, void* d_ws, size_t ws_size,
                              hipStream_t stream) {
  const float* x    = (const float*)d_in[0];
  const int*   esrc = (const int*)d_in[1];
  const int*   edst = (const int*)d_in[2];
  const float* ew   = (const float*)d_in[3];
  const float* W1   = (const float*)d_in[4];
  const float* b1   = (const float*)d_in[5];
  const float* W2   = (const float*)d_in[6];
  const float* b2   = (const float*)d_in[7];
  float* out = (float*)d_out;

  float* ws = (float*)d_ws;
  short* support1 = (short*)ws;                  // 25,600,000 bf16 (51.2 MB)
  short* hbuf     = (short*)(ws + 12800000);     // 25,600,000 bf16 (51.2 MB)
  short* support2 = (short*)(ws + 25600000);     //  4,800,000 bf16 (9.6 MB, stride 48)
  int2*  pairs    = (int2*)(ws + 30400000);      //  1,600,000 int2 (12.8 MB)
  int*   rowptr   = (int*)(ws + 33600000);       //    100,001 i
  int*   counts_t = (int*)(ws + 33700008);       //    100,000 i (per-node totals)
  int*   cursor   = (int*)(ws + 33800008);       //    100,000 i
  short* W1t      = (short*)(ws + 33900008);     //    131,072 bf16
  short* W2t      = (short*)(ws + 33965544);     //     12,288 bf16
  int*   bsums    = (int*)(ws + 33971688);       //        391 i
  int*   boffs    = bsums + 512;                 //        391 i
  int*   counts8  = (int*)(ws + 33972712);       //  800,000 i (8 shadows, 3.2 MB)

  hipMemsetAsync(counts8, 0, (size_t)NSHADOW * N_NODES * sizeof(int), stream);

  // 1) W1t prep (must precede K1's gemm1 blocks)
  w1t_only_kernel<<<(D_IN * D_HID + 511) / 512, 512, 0, stream>>>(W1, W1t);

  // 2) merged gemm1 + shadow hist + W2t-prep
  k1_gemm1_hist_w2t_kernel<<<G1_BLOCKS + HIST_BLOCKS + W2T_BLOCKS, 512, 0, stream>>>(
      x, W1t, support1, edst, counts8, W2, W2t);

  // 3) CSR scan + scatter
  block_sum_kernel<<<SCAN_BLOCKS, 256, 0, stream>>>(counts8, counts_t, bsums);
  bsum_scan_kernel<<<1, 512, 0, stream>>>(bsums, boffs);
  scan_apply_kernel<<<SCAN_BLOCKS, 256, 0, stream>>>(counts_t, boffs, rowptr, cursor);
  scatter_kernel<<<(N_EDGES + 255) / 256, 256, 0, stream>>>(esrc, edst, ew, cursor, pairs);

  // layer 1 aggregation
  spmm1_csr_kernel<<<(N_NODES + 3) / 4, 256, 0, stream>>>(support1, rowptr, pairs, b1, hbuf);

  // layer 2
  gemm2_mfma_kernel<<<(N_NODES + 127) / 128, 256, 0, stream>>>(hbuf, W2t, support2);
  spmm2_csr_kernel<<<(N_NODES + 7) / 8, 256, 0, stream>>>(support2, rowptr, pairs, b2, out);
}